// Round 1
// baseline (2201.036 us; speedup 1.0000x reference)
//
#include <hip/hip_runtime.h>
#include <hip/hip_bf16.h>

#define N_NODES 50000
#define N_EDGES 300000
#define IN_DIM 64
#define EMB 256
#define BN_EPS 1e-5f

typedef _Float16 half8 __attribute__((ext_vector_type(8)));
typedef float f32x4 __attribute__((ext_vector_type(4)));

__device__ __forceinline__ f32x4 mfma16(half8 a, half8 b, f32x4 c) {
    return __builtin_amdgcn_mfma_f32_16x16x32_f16(a, b, c, 0, 0, 0);
}

// ---------------- weight packing (once per launch) ----------------
// Fragment-packed fp16 weights: chunk index c = nt*KSTEPS*64 + ks*64 + lane,
// chunk holds 8 halves: W[ks*32 + (lane>>4)*8 + j][nt*16 + (lane&15)].
__global__ void pack_weights(const float* __restrict__ W1, const float* __restrict__ W2,
                             const float* __restrict__ Wenc, _Float16* __restrict__ wp) {
    int cid = blockIdx.x * 256 + threadIdx.x;
    if (cid < 18 * 8192) {
        int w = cid >> 13;            // which of 18 weights (li*2 + stage)
        int rem = cid & 8191;
        int nt = rem >> 9;            // 16 col tiles
        int ks = (rem >> 6) & 7;      // 8 k-steps
        int lane = rem & 63;
        int li = w >> 1;
        const float* src = ((w & 1) ? W2 : W1) + (size_t)li * EMB * EMB;
        _Float16* dst = wp + (size_t)cid * 8;
        int n = nt * 16 + (lane & 15);
        int kb = ks * 32 + (lane >> 4) * 8;
#pragma unroll
        for (int j = 0; j < 8; j++) dst[j] = (_Float16)src[(kb + j) * EMB + n];
    } else if (cid < 18 * 8192 + 2048) {
        int c = cid - 18 * 8192;      // encoder: K=64 -> 2 k-steps
        int nt = c >> 7;
        int ks = (c >> 6) & 1;
        int lane = c & 63;
        _Float16* dst = wp + (size_t)18 * 65536 + (size_t)c * 8;
        int n = nt * 16 + (lane & 15);
        int kb = ks * 32 + (lane >> 4) * 8;
#pragma unroll
        for (int j = 0; j < 8; j++) dst[j] = (_Float16)Wenc[(kb + j) * EMB + n];
    }
}

// ---------------- CSR build ----------------
__global__ void edge_count(const int* __restrict__ dst, unsigned* __restrict__ counts) {
    int e = blockIdx.x * 256 + threadIdx.x;
    if (e < N_EDGES) atomicAdd(&counts[dst[e]], 1u);
}

__global__ void scan_kernel(const unsigned* __restrict__ counts,
                            unsigned* __restrict__ rowptr, unsigned* __restrict__ cursor) {
    __shared__ unsigned sh[1024];
    __shared__ unsigned run;
    int t = threadIdx.x;
    if (t == 0) { run = 0; rowptr[0] = 0; }
    __syncthreads();
    for (int base = 0; base < N_NODES; base += 1024) {
        int i = base + t;
        unsigned v = (i < N_NODES) ? counts[i] : 0u;
        sh[t] = v;
        __syncthreads();
        for (int off = 1; off < 1024; off <<= 1) {
            unsigned add = (t >= off) ? sh[t - off] : 0u;
            __syncthreads();
            sh[t] += add;
            __syncthreads();
        }
        unsigned incl = sh[t];
        unsigned excl = incl - v;
        unsigned r0 = run;
        if (i < N_NODES) {
            rowptr[i + 1] = r0 + incl;
            cursor[i] = r0 + excl;
        }
        __syncthreads();
        if (t == 1023) run = r0 + incl;
        __syncthreads();
    }
}

__global__ void edge_fill(const int* __restrict__ src, const int* __restrict__ dst,
                          unsigned* __restrict__ cursor, unsigned* __restrict__ csr_src) {
    int e = blockIdx.x * 256 + threadIdx.x;
    if (e < N_EDGES) {
        unsigned pos = atomicAdd(&cursor[dst[e]], 1u);
        csr_src[pos] = (unsigned)src[e];
    }
}

// ---------------- encoder: g = x @ Wenc + benc (f16 MFMA, K=64) ----------------
__global__ void __launch_bounds__(256) enc_kernel(const float* __restrict__ x,
                                                  const _Float16* __restrict__ wp,
                                                  const float* __restrict__ benc,
                                                  float* __restrict__ g) {
    int w = threadIdx.x >> 6, lane = threadIdx.x & 63;
    int row0 = blockIdx.x * 64 + w * 16;
    if (row0 >= N_NODES) return;
    int rl = lane & 15, khi = lane >> 4;
    int rA = row0 + rl;
    f32x4 acc[16];
#pragma unroll
    for (int nt = 0; nt < 16; nt++) acc[nt] = (f32x4){0.f, 0.f, 0.f, 0.f};
#pragma unroll
    for (int ks = 0; ks < 2; ks++) {
        const float* ap = x + (size_t)rA * IN_DIM + ks * 32 + khi * 8;
        f32x4 a0 = *(const f32x4*)ap;
        f32x4 a1 = *(const f32x4*)(ap + 4);
        half8 a;
#pragma unroll
        for (int j = 0; j < 4; j++) { a[j] = (_Float16)a0[j]; a[4 + j] = (_Float16)a1[j]; }
        const half8* bp = (const half8*)wp + ks * 64 + lane;
#pragma unroll
        for (int nt = 0; nt < 16; nt++) acc[nt] = mfma16(a, bp[nt * 128], acc[nt]);
    }
#pragma unroll
    for (int nt = 0; nt < 16; nt++) {
        int col = nt * 16 + rl;
        float bias = benc[col];
#pragma unroll
        for (int r = 0; r < 4; r++)
            g[(size_t)(row0 + khi * 4 + r) * EMB + col] = acc[nt][r] + bias;
    }
}

// ---------------- aggregation: z = g + sum_{e: dst=n} g[src[e]] ----------------
__global__ void aggregate(const float* __restrict__ g, const unsigned* __restrict__ rowptr,
                          const unsigned* __restrict__ csr_src, float* __restrict__ z) {
    int n = blockIdx.x * 4 + (threadIdx.x >> 6);
    int lane = threadIdx.x & 63;
    if (n >= N_NODES) return;
    const f32x4* g4 = (const f32x4*)g;
    f32x4 acc = g4[(size_t)n * 64 + lane];
    unsigned beg = rowptr[n], end = rowptr[n + 1];
    for (unsigned e = beg; e < end; e++) {
        unsigned s = csr_src[e];
        acc += g4[(size_t)s * 64 + lane];
    }
    ((f32x4*)z)[(size_t)n * 64 + lane] = acc;
}

// ---------------- fused MLP: g = [relu](relu(z@W1+b1)@W2+b2) ----------------
__global__ void __launch_bounds__(256) mlp_kernel(const float* __restrict__ z,
                                                  const _Float16* __restrict__ w1p,
                                                  const float* __restrict__ b1,
                                                  const _Float16* __restrict__ w2p,
                                                  const float* __restrict__ b2,
                                                  float* __restrict__ g, int relu_out) {
    __shared__ _Float16 Tl[4][16][256];   // per-wave 16x256 fp16, XOR-swizzled
    int w = threadIdx.x >> 6, lane = threadIdx.x & 63;
    int row0 = blockIdx.x * 64 + w * 16;
    if (row0 >= N_NODES) return;
    int rl = lane & 15, khi = lane >> 4;
    int rA = row0 + rl;

    f32x4 acc[16];
#pragma unroll
    for (int nt = 0; nt < 16; nt++) acc[nt] = (f32x4){0.f, 0.f, 0.f, 0.f};
#pragma unroll
    for (int ks = 0; ks < 8; ks++) {
        const float* ap = z + (size_t)rA * EMB + ks * 32 + khi * 8;
        f32x4 a0 = *(const f32x4*)ap;
        f32x4 a1 = *(const f32x4*)(ap + 4);
        half8 a;
#pragma unroll
        for (int j = 0; j < 4; j++) { a[j] = (_Float16)a0[j]; a[4 + j] = (_Float16)a1[j]; }
        const half8* bp = (const half8*)w1p + ks * 64 + lane;
#pragma unroll
        for (int nt = 0; nt < 16; nt++) acc[nt] = mfma16(a, bp[nt * 512], acc[nt]);
    }
    // epilogue 1: bias + relu + swizzled LDS store of T (fp16)
#pragma unroll
    for (int nt = 0; nt < 16; nt++) {
        int col = nt * 16 + rl;
        float bias = b1[col];
#pragma unroll
        for (int r = 0; r < 4; r++) {
            int rloc = khi * 4 + r;
            float v = fmaxf(acc[nt][r] + bias, 0.f);
            Tl[w][rloc][col ^ ((rloc & 7) << 3)] = (_Float16)v;
        }
    }
    // stage 2 (same-wave LDS producer/consumer; compiler inserts lgkmcnt waits)
    f32x4 acc2[16];
#pragma unroll
    for (int nt = 0; nt < 16; nt++) acc2[nt] = (f32x4){0.f, 0.f, 0.f, 0.f};
#pragma unroll
    for (int ks = 0; ks < 8; ks++) {
        int eoff = (ks * 32 + khi * 8) ^ ((rl & 7) << 3);
        half8 a = *(const half8*)&Tl[w][rl][eoff];
        const half8* bp = (const half8*)w2p + ks * 64 + lane;
#pragma unroll
        for (int nt = 0; nt < 16; nt++) acc2[nt] = mfma16(a, bp[nt * 512], acc2[nt]);
    }
#pragma unroll
    for (int nt = 0; nt < 16; nt++) {
        int col = nt * 16 + rl;
        float bias = b2[col];
#pragma unroll
        for (int r = 0; r < 4; r++) {
            float v = acc2[nt][r] + bias;
            if (relu_out) v = fmaxf(v, 0.f);
            g[(size_t)(row0 + khi * 4 + r) * EMB + col] = v;
        }
    }
}

// ---------------- batchnorm ----------------
__global__ void bn_stats(const float* __restrict__ g, float* __restrict__ stats) {
    int col = threadIdx.x;
    int r0 = blockIdx.x * 128;
    float s = 0.f, s2 = 0.f;
    int rend = r0 + 128; if (rend > N_NODES) rend = N_NODES;
    for (int r = r0; r < rend; r++) {
        float v = g[(size_t)r * EMB + col];
        s += v; s2 += v * v;
    }
    atomicAdd(&stats[col], s);
    atomicAdd(&stats[EMB + col], s2);
}

__global__ void bn_finalize(const float* __restrict__ stats, const float* __restrict__ gamma,
                            const float* __restrict__ beta, float* __restrict__ ss) {
    int c = threadIdx.x;
    float mean = stats[c] * (1.f / N_NODES);
    float var = stats[EMB + c] * (1.f / N_NODES) - mean * mean;
    float scale = gamma[c] * rsqrtf(var + BN_EPS);
    ss[c] = scale;
    ss[EMB + c] = beta[c] - mean * scale;
}

__global__ void bn_apply(const float* __restrict__ gin, const float* __restrict__ ss,
                         float* __restrict__ gout, int relu) {
    int i = blockIdx.x * 256 + threadIdx.x;   // float4 index
    if (i >= N_NODES * 64) return;
    int c4 = (i & 63) * 4;
    f32x4 v = ((const f32x4*)gin)[i];
    f32x4 sc = *(const f32x4*)&ss[c4];
    f32x4 sh = *(const f32x4*)&ss[EMB + c4];
    f32x4 r;
#pragma unroll
    for (int j = 0; j < 4; j++) {
        float t = v[j] * sc[j] + sh[j];
        if (relu) t = fmaxf(t, 0.f);
        r[j] = t;
    }
    ((f32x4*)gout)[i] = r;
}

extern "C" void kernel_launch(void* const* d_in, const int* in_sizes, int n_in,
                              void* d_out, int out_size, void* d_ws, size_t ws_size,
                              hipStream_t stream) {
    const float* x     = (const float*)d_in[0];
    const int*   ei    = (const int*)d_in[1];
    const float* Wenc  = (const float*)d_in[2];
    const float* benc  = (const float*)d_in[3];
    const float* W1    = (const float*)d_in[4];
    const float* b1    = (const float*)d_in[5];
    const float* W2    = (const float*)d_in[6];
    const float* b2    = (const float*)d_in[7];
    const float* gamma = (const float*)d_in[8];
    const float* beta  = (const float*)d_in[9];
    float* out = (float*)d_out;

    char* p = (char*)d_ws;
    auto alloc = [&](size_t bytes) { void* q = (void*)p; p += (bytes + 255) & ~(size_t)255; return q; };
    float*     g       = (float*)alloc((size_t)N_NODES * EMB * 4);
    _Float16*  wp      = (_Float16*)alloc((size_t)(18 * 65536 + 16384) * 2);
    unsigned*  counts  = (unsigned*)alloc((size_t)N_NODES * 4);
    unsigned*  rowptr  = (unsigned*)alloc((size_t)(N_NODES + 1) * 4);
    unsigned*  cursor  = (unsigned*)alloc((size_t)N_NODES * 4);
    unsigned*  csr_src = (unsigned*)alloc((size_t)N_EDGES * 4);
    float*     stats   = (float*)alloc(512 * 4);
    float*     ss      = (float*)alloc(512 * 4);
    float* z = out;   // z scratch lives in d_out until the final bn_apply overwrites it

    hipMemsetAsync(counts, 0, (size_t)N_NODES * 4, stream);
    pack_weights<<<584, 256, 0, stream>>>(W1, W2, Wenc, wp);
    edge_count<<<(N_EDGES + 255) / 256, 256, 0, stream>>>(ei + N_EDGES, counts);
    scan_kernel<<<1, 1024, 0, stream>>>(counts, rowptr, cursor);
    edge_fill<<<(N_EDGES + 255) / 256, 256, 0, stream>>>(ei, ei + N_EDGES, cursor, csr_src);

    enc_kernel<<<(N_NODES + 63) / 64, 256, 0, stream>>>(x, wp + (size_t)18 * 65536, benc, g);

    for (int l = 0; l < 3; l++) {
        for (int i = 0; i < 3; i++) {
            int li = l * 3 + i;
            aggregate<<<N_NODES / 4, 256, 0, stream>>>(g, rowptr, csr_src, z);
            mlp_kernel<<<(N_NODES + 63) / 64, 256, 0, stream>>>(
                z, wp + (size_t)(li * 2) * 65536, b1 + li * EMB,
                wp + (size_t)(li * 2 + 1) * 65536, b2 + li * EMB, g, (i < 2) ? 1 : 0);
        }
        hipMemsetAsync(stats, 0, 512 * 4, stream);
        bn_stats<<<(N_NODES + 127) / 128, 256, 0, stream>>>(g, stats);
        bn_finalize<<<1, 256, 0, stream>>>(stats, gamma + l * EMB, beta + l * EMB, ss);
        bn_apply<<<(N_NODES * 64 + 255) / 256, 256, 0, stream>>>(
            g, ss, (l == 2) ? out : g, (l < 2) ? 1 : 0);
    }
}

// Round 3
// 1258.633 us; speedup vs baseline: 1.7488x; 1.7488x over previous
//
#include <hip/hip_runtime.h>
#include <hip/hip_bf16.h>

#define N_NODES 50000
#define N_EDGES 300000
#define IN_DIM 64
#define EMB 256
#define BN_EPS 1e-5f

typedef _Float16 half8 __attribute__((ext_vector_type(8)));
typedef _Float16 half4 __attribute__((ext_vector_type(4)));
typedef float f32x4 __attribute__((ext_vector_type(4)));

__device__ __forceinline__ f32x4 mfma16(half8 a, half8 b, f32x4 c) {
    return __builtin_amdgcn_mfma_f32_16x16x32_f16(a, b, c, 0, 0, 0);
}

// ---------------- weight packing (once per launch) ----------------
// Fragment-packed fp16 weights: chunk index c = nt*KSTEPS*64 + ks*64 + lane,
// chunk holds 8 halves: W[ks*32 + (lane>>4)*8 + j][nt*16 + (lane&15)].
__global__ void pack_weights(const float* __restrict__ W1, const float* __restrict__ W2,
                             const float* __restrict__ Wenc, _Float16* __restrict__ wp) {
    int cid = blockIdx.x * 256 + threadIdx.x;
    if (cid < 18 * 8192) {
        int w = cid >> 13;            // which of 18 weights (li*2 + stage)
        int rem = cid & 8191;
        int nt = rem >> 9;            // 16 col tiles
        int ks = (rem >> 6) & 7;      // 8 k-steps
        int lane = rem & 63;
        int li = w >> 1;
        const float* src = ((w & 1) ? W2 : W1) + (size_t)li * EMB * EMB;
        _Float16* dst = wp + (size_t)cid * 8;
        int n = nt * 16 + (lane & 15);
        int kb = ks * 32 + (lane >> 4) * 8;
#pragma unroll
        for (int j = 0; j < 8; j++) dst[j] = (_Float16)src[(kb + j) * EMB + n];
    } else if (cid < 18 * 8192 + 2048) {
        int c = cid - 18 * 8192;      // encoder: K=64 -> 2 k-steps
        int nt = c >> 7;
        int ks = (c >> 6) & 1;
        int lane = c & 63;
        _Float16* dst = wp + (size_t)18 * 65536 + (size_t)c * 8;
        int n = nt * 16 + (lane & 15);
        int kb = ks * 32 + (lane >> 4) * 8;
#pragma unroll
        for (int j = 0; j < 8; j++) dst[j] = (_Float16)Wenc[(kb + j) * EMB + n];
    }
}

// ---------------- CSR build ----------------
__global__ void edge_count(const int* __restrict__ dst, unsigned* __restrict__ counts) {
    int e = blockIdx.x * 256 + threadIdx.x;
    if (e < N_EDGES) atomicAdd(&counts[dst[e]], 1u);
}

__global__ void scan_kernel(const unsigned* __restrict__ counts,
                            unsigned* __restrict__ rowptr, unsigned* __restrict__ cursor) {
    __shared__ unsigned wsum[16];
    __shared__ unsigned run;
    int t = threadIdx.x, wv = t >> 6, lane = t & 63;
    if (t == 0) { run = 0; rowptr[0] = 0; }
    __syncthreads();
    for (int base = 0; base < N_NODES; base += 1024) {
        int i = base + t;
        unsigned v = (i < N_NODES) ? counts[i] : 0u;
        unsigned x = v;
#pragma unroll
        for (int off = 1; off < 64; off <<= 1) {
            unsigned y = __shfl_up(x, off, 64);
            if (lane >= off) x += y;
        }
        if (lane == 63) wsum[wv] = x;
        __syncthreads();
        if (wv == 0) {
            unsigned s = (lane < 16) ? wsum[lane] : 0u;
#pragma unroll
            for (int off = 1; off < 16; off <<= 1) {
                unsigned y = __shfl_up(s, off, 64);
                if (lane >= off) s += y;
            }
            if (lane < 16) wsum[lane] = s;
        }
        __syncthreads();
        unsigned waveoff = (wv > 0) ? wsum[wv - 1] : 0u;
        unsigned incl = run + waveoff + x;
        if (i < N_NODES) { rowptr[i + 1] = incl; cursor[i] = incl - v; }
        __syncthreads();
        if (t == 1023) run = incl;   // lane63 of wave15: global running total
        __syncthreads();
    }
}

__global__ void edge_fill(const int* __restrict__ src, const int* __restrict__ dst,
                          unsigned* __restrict__ cursor, unsigned* __restrict__ csr_src) {
    int e = blockIdx.x * 256 + threadIdx.x;
    if (e < N_EDGES) {
        unsigned pos = atomicAdd(&cursor[dst[e]], 1u);
        csr_src[pos] = (unsigned)src[e];
    }
}

// ---------------- encoder: g = x @ Wenc + benc (col-split waves) ----------------
__global__ void __launch_bounds__(256) enc_kernel(const float* __restrict__ x,
                                                  const _Float16* __restrict__ wenc,
                                                  const float* __restrict__ benc,
                                                  float* __restrict__ g) {
    int t = threadIdx.x, w = t >> 6, lane = t & 63;
    int rl = lane & 15, khi = lane >> 4;
    int row0 = blockIdx.x * 64;
    f32x4 acc[4][4];
#pragma unroll
    for (int rf = 0; rf < 4; rf++)
#pragma unroll
        for (int nt = 0; nt < 4; nt++) acc[rf][nt] = (f32x4){0.f, 0.f, 0.f, 0.f};
    const half8* bp = (const half8*)wenc + (size_t)(w * 4) * 128 + lane;
#pragma unroll
    for (int ks = 0; ks < 2; ks++) {
        half8 a[4];
#pragma unroll
        for (int rf = 0; rf < 4; rf++) {
            int n = row0 + rf * 16 + rl;
            f32x4 a0 = (f32x4){0.f,0.f,0.f,0.f}, a1 = (f32x4){0.f,0.f,0.f,0.f};
            if (n < N_NODES) {
                const float* ap = x + (size_t)n * IN_DIM + ks * 32 + khi * 8;
                a0 = *(const f32x4*)ap;
                a1 = *(const f32x4*)(ap + 4);
            }
#pragma unroll
            for (int j = 0; j < 4; j++) { a[rf][j] = (_Float16)a0[j]; a[rf][4 + j] = (_Float16)a1[j]; }
        }
        half8 b[4];
#pragma unroll
        for (int nt = 0; nt < 4; nt++) b[nt] = bp[nt * 128 + ks * 64];
#pragma unroll
        for (int rf = 0; rf < 4; rf++)
#pragma unroll
            for (int nt = 0; nt < 4; nt++) acc[rf][nt] = mfma16(a[rf], b[nt], acc[rf][nt]);
    }
#pragma unroll
    for (int nt = 0; nt < 4; nt++) {
        int col = w * 64 + nt * 16 + rl;
        float bias = benc[col];
#pragma unroll
        for (int rf = 0; rf < 4; rf++)
#pragma unroll
            for (int r = 0; r < 4; r++) {
                int n = row0 + rf * 16 + khi * 4 + r;
                if (n < N_NODES) g[(size_t)n * EMB + col] = acc[rf][nt][r] + bias;
            }
    }
}

// ---------------- fused conv: gather(+bn affine+relu) -> MLP(2 GEMMs) -> [stats] ----------------
__global__ void __launch_bounds__(256, 3) conv_kernel(
    const float* __restrict__ gin, const unsigned* __restrict__ rowptr,
    const unsigned* __restrict__ csr_src,
    const _Float16* __restrict__ w1p, const float* __restrict__ b1,
    const _Float16* __restrict__ w2p, const float* __restrict__ b2,
    float* __restrict__ gout, const float* __restrict__ ssp,
    float* __restrict__ statp, int relu_out)
{
    __shared__ __align__(16) _Float16 zt[64 * 256];   // z tile, then reused as T tile
    int t = threadIdx.x, w = t >> 6, lane = t & 63;
    int rl = lane & 15, khi = lane >> 4;
    int row0 = blockIdx.x * 64;
    const f32x4* g4 = (const f32x4*)gin;

    bool affine = (ssp != nullptr);
    f32x4 sc = (f32x4){1.f,1.f,1.f,1.f}, sh = (f32x4){0.f,0.f,0.f,0.f};
    if (affine) { sc = *(const f32x4*)&ssp[lane * 4]; sh = *(const f32x4*)&ssp[EMB + lane * 4]; }

    auto tv = [&](f32x4 v) -> f32x4 {
        if (affine) {
#pragma unroll
            for (int j = 0; j < 4; j++) v[j] = fmaxf(v[j] * sc[j] + sh[j], 0.f);
        }
        return v;
    };

    // ---- gather phase: wave w builds z rows [w*16, w*16+16) into LDS fp16 ----
    for (int rr = 0; rr < 16; rr++) {
        int rloc = w * 16 + rr;
        int n = row0 + rloc;
        f32x4 acc = (f32x4){0.f, 0.f, 0.f, 0.f};
        if (n < N_NODES) {
            acc = tv(g4[(size_t)n * 64 + lane]);
            unsigned e = rowptr[n], end = rowptr[n + 1];
            for (; e + 4 <= end; e += 4) {
                unsigned s0 = csr_src[e], s1 = csr_src[e + 1];
                unsigned s2 = csr_src[e + 2], s3 = csr_src[e + 3];
                f32x4 v0 = g4[(size_t)s0 * 64 + lane];
                f32x4 v1 = g4[(size_t)s1 * 64 + lane];
                f32x4 v2 = g4[(size_t)s2 * 64 + lane];
                f32x4 v3 = g4[(size_t)s3 * 64 + lane];
                acc += tv(v0); acc += tv(v1); acc += tv(v2); acc += tv(v3);
            }
            for (; e < end; e++) acc += tv(g4[(size_t)csr_src[e] * 64 + lane]);
        }
        half4 h;
#pragma unroll
        for (int j = 0; j < 4; j++) h[j] = (_Float16)acc[j];
        *(half4*)&zt[rloc * 256 + ((lane * 4) ^ ((rloc & 15) << 3))] = h;
    }
    __syncthreads();

    // ---- stage 1: T = relu(z @ W1 + b1), wave w owns cols [w*64, w*64+64) ----
    f32x4 acc1[4][4];
#pragma unroll
    for (int rf = 0; rf < 4; rf++)
#pragma unroll
        for (int nt = 0; nt < 4; nt++) acc1[rf][nt] = (f32x4){0.f, 0.f, 0.f, 0.f};
    {
        const half8* bp = (const half8*)w1p + (size_t)(w * 4) * 512 + lane;
#pragma unroll
        for (int ks = 0; ks < 8; ks++) {
            half8 a[4];
#pragma unroll
            for (int rf = 0; rf < 4; rf++) {
                int row = rf * 16 + rl;
                a[rf] = *(const half8*)&zt[row * 256 + ((ks * 32 + khi * 8) ^ ((row & 15) << 3))];
            }
            half8 b[4];
#pragma unroll
            for (int nt = 0; nt < 4; nt++) b[nt] = bp[nt * 512 + ks * 64];
#pragma unroll
            for (int rf = 0; rf < 4; rf++)
#pragma unroll
                for (int nt = 0; nt < 4; nt++) acc1[rf][nt] = mfma16(a[rf], b[nt], acc1[rf][nt]);
        }
    }
    __syncthreads();   // all stage-1 reads of zt complete
#pragma unroll
    for (int nt = 0; nt < 4; nt++) {
        int col = w * 64 + nt * 16 + rl;
        float bias = b1[col];
#pragma unroll
        for (int rf = 0; rf < 4; rf++)
#pragma unroll
            for (int r = 0; r < 4; r++) {
                int row = rf * 16 + khi * 4 + r;
                float v = fmaxf(acc1[rf][nt][r] + bias, 0.f);
                zt[row * 256 + (col ^ ((row & 15) << 3))] = (_Float16)v;
            }
    }
    __syncthreads();   // T tile complete

    // ---- stage 2: g = T @ W2 + b2 (+relu) ----
    f32x4 acc2[4][4];
#pragma unroll
    for (int rf = 0; rf < 4; rf++)
#pragma unroll
        for (int nt = 0; nt < 4; nt++) acc2[rf][nt] = (f32x4){0.f, 0.f, 0.f, 0.f};
    {
        const half8* bp = (const half8*)w2p + (size_t)(w * 4) * 512 + lane;
#pragma unroll
        for (int ks = 0; ks < 8; ks++) {
            half8 a[4];
#pragma unroll
            for (int rf = 0; rf < 4; rf++) {
                int row = rf * 16 + rl;
                a[rf] = *(const half8*)&zt[row * 256 + ((ks * 32 + khi * 8) ^ ((row & 15) << 3))];
            }
            half8 b[4];
#pragma unroll
            for (int nt = 0; nt < 4; nt++) b[nt] = bp[nt * 512 + ks * 64];
#pragma unroll
            for (int rf = 0; rf < 4; rf++)
#pragma unroll
                for (int nt = 0; nt < 4; nt++) acc2[rf][nt] = mfma16(a[rf], b[nt], acc2[rf][nt]);
        }
    }
#pragma unroll
    for (int nt = 0; nt < 4; nt++) {
        int col = w * 64 + nt * 16 + rl;
        float bias = b2[col];
        float sS = 0.f, s2S = 0.f;
#pragma unroll
        for (int rf = 0; rf < 4; rf++)
#pragma unroll
            for (int r = 0; r < 4; r++) {
                int row = rf * 16 + khi * 4 + r;
                int n = row0 + row;
                float v = acc2[rf][nt][r] + bias;
                if (relu_out) v = fmaxf(v, 0.f);
                if (n < N_NODES) {
                    gout[(size_t)n * EMB + col] = v;
                    sS += v; s2S += v * v;
                }
            }
        if (statp) {
            sS += __shfl_xor(sS, 16); s2S += __shfl_xor(s2S, 16);
            sS += __shfl_xor(sS, 32); s2S += __shfl_xor(s2S, 32);
            if (khi == 0) {
                atomicAdd(&statp[col], sS);
                atomicAdd(&statp[EMB + col], s2S);
            }
        }
    }
}

// ---------------- batchnorm finalize + final apply ----------------
__global__ void bn_finalize(const float* __restrict__ stats, const float* __restrict__ gamma,
                            const float* __restrict__ beta, float* __restrict__ ss) {
    int c = threadIdx.x;
    float mean = stats[c] * (1.f / N_NODES);
    float var = stats[EMB + c] * (1.f / N_NODES) - mean * mean;
    float scale = gamma[c] * rsqrtf(var + BN_EPS);
    ss[c] = scale;
    ss[EMB + c] = beta[c] - mean * scale;
}

__global__ void bn_apply(const float* __restrict__ gin, const float* __restrict__ ss,
                         float* __restrict__ gout) {
    int i = blockIdx.x * 256 + threadIdx.x;   // float4 index
    if (i >= N_NODES * 64) return;
    int c4 = (i & 63) * 4;
    f32x4 v = ((const f32x4*)gin)[i];
    f32x4 sc = *(const f32x4*)&ss[c4];
    f32x4 sh = *(const f32x4*)&ss[EMB + c4];
    f32x4 r;
#pragma unroll
    for (int j = 0; j < 4; j++) r[j] = v[j] * sc[j] + sh[j];
    ((f32x4*)gout)[i] = r;
}

extern "C" void kernel_launch(void* const* d_in, const int* in_sizes, int n_in,
                              void* d_out, int out_size, void* d_ws, size_t ws_size,
                              hipStream_t stream) {
    const float* x     = (const float*)d_in[0];
    const int*   ei    = (const int*)d_in[1];
    const float* Wenc  = (const float*)d_in[2];
    const float* benc  = (const float*)d_in[3];
    const float* W1    = (const float*)d_in[4];
    const float* b1    = (const float*)d_in[5];
    const float* W2    = (const float*)d_in[6];
    const float* b2    = (const float*)d_in[7];
    const float* gamma = (const float*)d_in[8];
    const float* beta  = (const float*)d_in[9];
    float* out = (float*)d_out;

    char* p = (char*)d_ws;
    auto alloc = [&](size_t bytes) { void* q = (void*)p; p += (bytes + 255) & ~(size_t)255; return q; };
    float*     g0      = (float*)alloc((size_t)N_NODES * EMB * 4);
    _Float16*  wp      = (_Float16*)alloc((size_t)(18 * 65536 + 16384) * 2);
    unsigned*  counts  = (unsigned*)alloc((size_t)N_NODES * 4);
    unsigned*  rowptr  = (unsigned*)alloc((size_t)(N_NODES + 1) * 4);
    unsigned*  cursor  = (unsigned*)alloc((size_t)N_NODES * 4);
    unsigned*  csr_src = (unsigned*)alloc((size_t)N_EDGES * 4);
    float*     stats   = (float*)alloc(3 * 512 * 4);
    float*     ss      = (float*)alloc(3 * 512 * 4);

    hipMemsetAsync(counts, 0, (size_t)N_NODES * 4, stream);
    hipMemsetAsync(stats, 0, 3 * 512 * 4, stream);
    pack_weights<<<584, 256, 0, stream>>>(W1, W2, Wenc, wp);
    edge_count<<<(N_EDGES + 255) / 256, 256, 0, stream>>>(ei + N_EDGES, counts);
    scan_kernel<<<1, 1024, 0, stream>>>(counts, rowptr, cursor);
    edge_fill<<<(N_EDGES + 255) / 256, 256, 0, stream>>>(ei, ei + N_EDGES, cursor, csr_src);

    enc_kernel<<<782, 256, 0, stream>>>(x, wp + (size_t)18 * 65536, benc, g0);

    float* cur = g0;
    float* nxt = out;
    for (int l = 0; l < 3; l++) {
        for (int i = 0; i < 3; i++) {
            int li = l * 3 + i;
            const float* ssp = (i == 0 && l > 0) ? (ss + (size_t)(l - 1) * 512) : nullptr;
            float* statp = (i == 2) ? (stats + (size_t)l * 512) : nullptr;
            conv_kernel<<<782, 256, 0, stream>>>(
                cur, rowptr, csr_src,
                wp + (size_t)(li * 2) * 65536, b1 + li * EMB,
                wp + (size_t)(li * 2 + 1) * 65536, b2 + li * EMB,
                nxt, ssp, statp, (i < 2) ? 1 : 0);
            float* tmp = cur; cur = nxt; nxt = tmp;
        }
        bn_finalize<<<1, 256, 0, stream>>>(stats + (size_t)l * 512, gamma + l * EMB,
                                           beta + l * EMB, ss + (size_t)l * 512);
    }
    // after 9 convs (odd count) cur == out; final BN applied in-place
    bn_apply<<<(N_NODES * 64 + 255) / 256, 256, 0, stream>>>(out, ss + 2 * 512, out);
}

// Round 4
// 1255.201 us; speedup vs baseline: 1.7535x; 1.0027x over previous
//
#include <hip/hip_runtime.h>
#include <hip/hip_bf16.h>

#define N_NODES 50000
#define N_EDGES 300000
#define IN_DIM 64
#define EMB 256
#define BN_EPS 1e-5f

typedef _Float16 half8 __attribute__((ext_vector_type(8)));
typedef _Float16 half4 __attribute__((ext_vector_type(4)));
typedef float f32x4 __attribute__((ext_vector_type(4)));

__device__ __forceinline__ f32x4 mfma16(half8 a, half8 b, f32x4 c) {
    return __builtin_amdgcn_mfma_f32_16x16x32_f16(a, b, c, 0, 0, 0);
}

__device__ __forceinline__ f32x4 h2f(half4 h) {
    f32x4 r;
#pragma unroll
    for (int j = 0; j < 4; j++) r[j] = (float)h[j];
    return r;
}

// ---------------- weight packing (once per launch) ----------------
// Fragment-packed fp16 weights: chunk index c = nt*KSTEPS*64 + ks*64 + lane,
// chunk holds 8 halves: W[ks*32 + (lane>>4)*8 + j][nt*16 + (lane&15)].
__global__ void pack_weights(const float* __restrict__ W1, const float* __restrict__ W2,
                             const float* __restrict__ Wenc, _Float16* __restrict__ wp) {
    int cid = blockIdx.x * 256 + threadIdx.x;
    if (cid < 18 * 8192) {
        int w = cid >> 13;            // which of 18 weights (li*2 + stage)
        int rem = cid & 8191;
        int nt = rem >> 9;            // 16 col tiles
        int ks = (rem >> 6) & 7;      // 8 k-steps
        int lane = rem & 63;
        int li = w >> 1;
        const float* src = ((w & 1) ? W2 : W1) + (size_t)li * EMB * EMB;
        _Float16* dst = wp + (size_t)cid * 8;
        int n = nt * 16 + (lane & 15);
        int kb = ks * 32 + (lane >> 4) * 8;
#pragma unroll
        for (int j = 0; j < 8; j++) dst[j] = (_Float16)src[(kb + j) * EMB + n];
    } else if (cid < 18 * 8192 + 2048) {
        int c = cid - 18 * 8192;      // encoder: K=64 -> 2 k-steps
        int nt = c >> 7;
        int ks = (c >> 6) & 1;
        int lane = c & 63;
        _Float16* dst = wp + (size_t)18 * 65536 + (size_t)c * 8;
        int n = nt * 16 + (lane & 15);
        int kb = ks * 32 + (lane >> 4) * 8;
#pragma unroll
        for (int j = 0; j < 8; j++) dst[j] = (_Float16)Wenc[(kb + j) * EMB + n];
    }
}

// ---------------- CSR build ----------------
__global__ void edge_count(const int* __restrict__ dst, unsigned* __restrict__ counts) {
    int e = blockIdx.x * 256 + threadIdx.x;
    if (e < N_EDGES) atomicAdd(&counts[dst[e]], 1u);
}

__global__ void scan_kernel(const unsigned* __restrict__ counts,
                            unsigned* __restrict__ rowptr, unsigned* __restrict__ cursor) {
    __shared__ unsigned wsum[16];
    __shared__ unsigned run;
    int t = threadIdx.x, wv = t >> 6, lane = t & 63;
    if (t == 0) { run = 0; rowptr[0] = 0; }
    __syncthreads();
    for (int base = 0; base < N_NODES; base += 1024) {
        int i = base + t;
        unsigned v = (i < N_NODES) ? counts[i] : 0u;
        unsigned x = v;
#pragma unroll
        for (int off = 1; off < 64; off <<= 1) {
            unsigned y = __shfl_up(x, off, 64);
            if (lane >= off) x += y;
        }
        if (lane == 63) wsum[wv] = x;
        __syncthreads();
        if (wv == 0) {
            unsigned s = (lane < 16) ? wsum[lane] : 0u;
#pragma unroll
            for (int off = 1; off < 16; off <<= 1) {
                unsigned y = __shfl_up(s, off, 64);
                if (lane >= off) s += y;
            }
            if (lane < 16) wsum[lane] = s;
        }
        __syncthreads();
        unsigned waveoff = (wv > 0) ? wsum[wv - 1] : 0u;
        unsigned incl = run + waveoff + x;
        if (i < N_NODES) { rowptr[i + 1] = incl; cursor[i] = incl - v; }
        __syncthreads();
        if (t == 1023) run = incl;   // lane63 of wave15: global running total
        __syncthreads();
    }
}

__global__ void edge_fill(const int* __restrict__ src, const int* __restrict__ dst,
                          unsigned* __restrict__ cursor, unsigned* __restrict__ csr_src) {
    int e = blockIdx.x * 256 + threadIdx.x;
    if (e < N_EDGES) {
        unsigned pos = atomicAdd(&cursor[dst[e]], 1u);
        csr_src[pos] = (unsigned)src[e];
    }
}

// ---------------- encoder: g = x @ Wenc + benc (fp16 out) ----------------
__global__ void __launch_bounds__(256) enc_kernel(const float* __restrict__ x,
                                                  const _Float16* __restrict__ wenc,
                                                  const float* __restrict__ benc,
                                                  _Float16* __restrict__ g) {
    int t = threadIdx.x, w = t >> 6, lane = t & 63;
    int rl = lane & 15, khi = lane >> 4;
    int row0 = blockIdx.x * 64;
    f32x4 acc[4][4];
#pragma unroll
    for (int rf = 0; rf < 4; rf++)
#pragma unroll
        for (int nt = 0; nt < 4; nt++) acc[rf][nt] = (f32x4){0.f, 0.f, 0.f, 0.f};
    const half8* bp = (const half8*)wenc + (size_t)(w * 4) * 128 + lane;
#pragma unroll
    for (int ks = 0; ks < 2; ks++) {
        half8 a[4];
#pragma unroll
        for (int rf = 0; rf < 4; rf++) {
            int n = row0 + rf * 16 + rl;
            f32x4 a0 = (f32x4){0.f,0.f,0.f,0.f}, a1 = (f32x4){0.f,0.f,0.f,0.f};
            if (n < N_NODES) {
                const float* ap = x + (size_t)n * IN_DIM + ks * 32 + khi * 8;
                a0 = *(const f32x4*)ap;
                a1 = *(const f32x4*)(ap + 4);
            }
#pragma unroll
            for (int j = 0; j < 4; j++) { a[rf][j] = (_Float16)a0[j]; a[rf][4 + j] = (_Float16)a1[j]; }
        }
        half8 b[4];
#pragma unroll
        for (int nt = 0; nt < 4; nt++) b[nt] = bp[nt * 128 + ks * 64];
#pragma unroll
        for (int rf = 0; rf < 4; rf++)
#pragma unroll
            for (int nt = 0; nt < 4; nt++) acc[rf][nt] = mfma16(a[rf], b[nt], acc[rf][nt]);
    }
#pragma unroll
    for (int nt = 0; nt < 4; nt++) {
        int col = w * 64 + nt * 16 + rl;
        float bias = benc[col];
#pragma unroll
        for (int rf = 0; rf < 4; rf++)
#pragma unroll
            for (int r = 0; r < 4; r++) {
                int n = row0 + rf * 16 + khi * 4 + r;
                if (n < N_NODES) g[(size_t)n * EMB + col] = (_Float16)(acc[rf][nt][r] + bias);
            }
    }
}

// ---------------- fused conv: gather(+bn affine+relu) -> MLP(2 GEMMs) -> [stats] ----------------
__global__ void __launch_bounds__(256, 3) conv_kernel(
    const _Float16* __restrict__ gin, const unsigned* __restrict__ rowptr,
    const unsigned* __restrict__ csr_src,
    const _Float16* __restrict__ w1p, const float* __restrict__ b1,
    const _Float16* __restrict__ w2p, const float* __restrict__ b2,
    _Float16* __restrict__ gout_h, float* __restrict__ gout_f,
    const float* __restrict__ ssp, float* __restrict__ statp, int relu_out)
{
    __shared__ __align__(16) _Float16 zt[64 * 256];   // z tile, then reused as T tile
    int t = threadIdx.x, w = t >> 6, lane = t & 63;
    int rl = lane & 15, khi = lane >> 4;
    int row0 = blockIdx.x * 64;
    const half4* g4 = (const half4*)gin;

    bool affine = (ssp != nullptr);
    f32x4 sc = (f32x4){1.f,1.f,1.f,1.f}, sh = (f32x4){0.f,0.f,0.f,0.f};
    if (affine) { sc = *(const f32x4*)&ssp[lane * 4]; sh = *(const f32x4*)&ssp[EMB + lane * 4]; }

    auto tv = [&](f32x4 v) -> f32x4 {
        if (affine) {
#pragma unroll
            for (int j = 0; j < 4; j++) v[j] = fmaxf(v[j] * sc[j] + sh[j], 0.f);
        }
        return v;
    };

    // ---- gather phase: wave w builds z rows [w*16, w*16+16) into LDS fp16 ----
    for (int rr = 0; rr < 16; rr++) {
        int rloc = w * 16 + rr;
        int n = row0 + rloc;
        f32x4 acc = (f32x4){0.f, 0.f, 0.f, 0.f};
        if (n < N_NODES) {
            acc = tv(h2f(g4[(size_t)n * 64 + lane]));
            unsigned e = rowptr[n], end = rowptr[n + 1];
            for (; e + 4 <= end; e += 4) {
                unsigned s0 = csr_src[e], s1 = csr_src[e + 1];
                unsigned s2 = csr_src[e + 2], s3 = csr_src[e + 3];
                half4 v0 = g4[(size_t)s0 * 64 + lane];
                half4 v1 = g4[(size_t)s1 * 64 + lane];
                half4 v2 = g4[(size_t)s2 * 64 + lane];
                half4 v3 = g4[(size_t)s3 * 64 + lane];
                acc += tv(h2f(v0)); acc += tv(h2f(v1));
                acc += tv(h2f(v2)); acc += tv(h2f(v3));
            }
            for (; e < end; e++) acc += tv(h2f(g4[(size_t)csr_src[e] * 64 + lane]));
        }
        half4 h;
#pragma unroll
        for (int j = 0; j < 4; j++) h[j] = (_Float16)acc[j];
        *(half4*)&zt[rloc * 256 + ((lane * 4) ^ ((rloc & 15) << 3))] = h;
    }
    __syncthreads();

    // ---- stage 1: T = relu(z @ W1 + b1), wave w owns cols [w*64, w*64+64) ----
    f32x4 acc1[4][4];
#pragma unroll
    for (int rf = 0; rf < 4; rf++)
#pragma unroll
        for (int nt = 0; nt < 4; nt++) acc1[rf][nt] = (f32x4){0.f, 0.f, 0.f, 0.f};
    {
        const half8* bp = (const half8*)w1p + (size_t)(w * 4) * 512 + lane;
#pragma unroll
        for (int ks = 0; ks < 8; ks++) {
            half8 a[4];
#pragma unroll
            for (int rf = 0; rf < 4; rf++) {
                int row = rf * 16 + rl;
                a[rf] = *(const half8*)&zt[row * 256 + ((ks * 32 + khi * 8) ^ ((row & 15) << 3))];
            }
            half8 b[4];
#pragma unroll
            for (int nt = 0; nt < 4; nt++) b[nt] = bp[nt * 512 + ks * 64];
#pragma unroll
            for (int rf = 0; rf < 4; rf++)
#pragma unroll
                for (int nt = 0; nt < 4; nt++) acc1[rf][nt] = mfma16(a[rf], b[nt], acc1[rf][nt]);
        }
    }
    __syncthreads();   // all stage-1 reads of zt complete
#pragma unroll
    for (int nt = 0; nt < 4; nt++) {
        int col = w * 64 + nt * 16 + rl;
        float bias = b1[col];
#pragma unroll
        for (int rf = 0; rf < 4; rf++)
#pragma unroll
            for (int r = 0; r < 4; r++) {
                int row = rf * 16 + khi * 4 + r;
                float v = fmaxf(acc1[rf][nt][r] + bias, 0.f);
                zt[row * 256 + (col ^ ((row & 15) << 3))] = (_Float16)v;
            }
    }
    __syncthreads();   // T tile complete

    // ---- stage 2: g = T @ W2 + b2 (+relu) ----
    f32x4 acc2[4][4];
#pragma unroll
    for (int rf = 0; rf < 4; rf++)
#pragma unroll
        for (int nt = 0; nt < 4; nt++) acc2[rf][nt] = (f32x4){0.f, 0.f, 0.f, 0.f};
    {
        const half8* bp = (const half8*)w2p + (size_t)(w * 4) * 512 + lane;
#pragma unroll
        for (int ks = 0; ks < 8; ks++) {
            half8 a[4];
#pragma unroll
            for (int rf = 0; rf < 4; rf++) {
                int row = rf * 16 + rl;
                a[rf] = *(const half8*)&zt[row * 256 + ((ks * 32 + khi * 8) ^ ((row & 15) << 3))];
            }
            half8 b[4];
#pragma unroll
            for (int nt = 0; nt < 4; nt++) b[nt] = bp[nt * 512 + ks * 64];
#pragma unroll
            for (int rf = 0; rf < 4; rf++)
#pragma unroll
                for (int nt = 0; nt < 4; nt++) acc2[rf][nt] = mfma16(a[rf], b[nt], acc2[rf][nt]);
        }
    }
    bool wf = (gout_f != nullptr);
#pragma unroll
    for (int nt = 0; nt < 4; nt++) {
        int col = w * 64 + nt * 16 + rl;
        float bias = b2[col];
        float sS = 0.f, s2S = 0.f;
#pragma unroll
        for (int rf = 0; rf < 4; rf++)
#pragma unroll
            for (int r = 0; r < 4; r++) {
                int row = rf * 16 + khi * 4 + r;
                int n = row0 + row;
                float v = acc2[rf][nt][r] + bias;
                if (relu_out) v = fmaxf(v, 0.f);
                if (n < N_NODES) {
                    if (wf) gout_f[(size_t)n * EMB + col] = v;
                    else    gout_h[(size_t)n * EMB + col] = (_Float16)v;
                    sS += v; s2S += v * v;
                }
            }
        if (statp) {
            sS += __shfl_xor(sS, 16); s2S += __shfl_xor(s2S, 16);
            sS += __shfl_xor(sS, 32); s2S += __shfl_xor(s2S, 32);
            if (khi == 0) {
                atomicAdd(&statp[col], sS);
                atomicAdd(&statp[EMB + col], s2S);
            }
        }
    }
}

// ---------------- batchnorm finalize + final apply ----------------
__global__ void bn_finalize(const float* __restrict__ stats, const float* __restrict__ gamma,
                            const float* __restrict__ beta, float* __restrict__ ss) {
    int c = threadIdx.x;
    float mean = stats[c] * (1.f / N_NODES);
    float var = stats[EMB + c] * (1.f / N_NODES) - mean * mean;
    float scale = gamma[c] * rsqrtf(var + BN_EPS);
    ss[c] = scale;
    ss[EMB + c] = beta[c] - mean * scale;
}

__global__ void bn_apply(const float* __restrict__ gin, const float* __restrict__ ss,
                         float* __restrict__ gout) {
    int i = blockIdx.x * 256 + threadIdx.x;   // float4 index
    if (i >= N_NODES * 64) return;
    int c4 = (i & 63) * 4;
    f32x4 v = ((const f32x4*)gin)[i];
    f32x4 sc = *(const f32x4*)&ss[c4];
    f32x4 sh = *(const f32x4*)&ss[EMB + c4];
    f32x4 r;
#pragma unroll
    for (int j = 0; j < 4; j++) r[j] = v[j] * sc[j] + sh[j];
    ((f32x4*)gout)[i] = r;
}

extern "C" void kernel_launch(void* const* d_in, const int* in_sizes, int n_in,
                              void* d_out, int out_size, void* d_ws, size_t ws_size,
                              hipStream_t stream) {
    const float* x     = (const float*)d_in[0];
    const int*   ei    = (const int*)d_in[1];
    const float* Wenc  = (const float*)d_in[2];
    const float* benc  = (const float*)d_in[3];
    const float* W1    = (const float*)d_in[4];
    const float* b1    = (const float*)d_in[5];
    const float* W2    = (const float*)d_in[6];
    const float* b2    = (const float*)d_in[7];
    const float* gamma = (const float*)d_in[8];
    const float* beta  = (const float*)d_in[9];
    float* out = (float*)d_out;

    char* p = (char*)d_ws;
    auto alloc = [&](size_t bytes) { void* q = (void*)p; p += (bytes + 255) & ~(size_t)255; return q; };
    _Float16*  gh0     = (_Float16*)alloc((size_t)N_NODES * EMB * 2);
    _Float16*  gh1     = (_Float16*)alloc((size_t)N_NODES * EMB * 2);
    _Float16*  wp      = (_Float16*)alloc((size_t)(18 * 65536 + 16384) * 2);
    unsigned*  counts  = (unsigned*)alloc((size_t)N_NODES * 4);
    unsigned*  rowptr  = (unsigned*)alloc((size_t)(N_NODES + 1) * 4);
    unsigned*  cursor  = (unsigned*)alloc((size_t)N_NODES * 4);
    unsigned*  csr_src = (unsigned*)alloc((size_t)N_EDGES * 4);
    float*     stats   = (float*)alloc(3 * 512 * 4);
    float*     ss      = (float*)alloc(3 * 512 * 4);

    hipMemsetAsync(counts, 0, (size_t)N_NODES * 4, stream);
    hipMemsetAsync(stats, 0, 3 * 512 * 4, stream);
    pack_weights<<<584, 256, 0, stream>>>(W1, W2, Wenc, wp);
    edge_count<<<(N_EDGES + 255) / 256, 256, 0, stream>>>(ei + N_EDGES, counts);
    scan_kernel<<<1, 1024, 0, stream>>>(counts, rowptr, cursor);
    edge_fill<<<(N_EDGES + 255) / 256, 256, 0, stream>>>(ei, ei + N_EDGES, cursor, csr_src);

    enc_kernel<<<782, 256, 0, stream>>>(x, wp + (size_t)18 * 65536, benc, gh0);

    _Float16* cur = gh0;
    _Float16* nxt = gh1;
    for (int l = 0; l < 3; l++) {
        for (int i = 0; i < 3; i++) {
            int li = l * 3 + i;
            bool last = (l == 2 && i == 2);
            const float* ssp = (i == 0 && l > 0) ? (ss + (size_t)(l - 1) * 512) : nullptr;
            float* statp = (i == 2) ? (stats + (size_t)l * 512) : nullptr;
            conv_kernel<<<782, 256, 0, stream>>>(
                cur, rowptr, csr_src,
                wp + (size_t)(li * 2) * 65536, b1 + li * EMB,
                wp + (size_t)(li * 2 + 1) * 65536, b2 + li * EMB,
                last ? nullptr : nxt, last ? out : nullptr,
                ssp, statp, (i < 2) ? 1 : 0);
            if (!last) { _Float16* tmp = cur; cur = nxt; nxt = tmp; }
        }
        bn_finalize<<<1, 256, 0, stream>>>(stats + (size_t)l * 512, gamma + l * EMB,
                                           beta + l * EMB, ss + (size_t)l * 512);
    }
    // final BN applied in-place on fp32 out
    bn_apply<<<(N_NODES * 64 + 255) / 256, 256, 0, stream>>>(out, ss + 2 * 512, out);
}

// Round 5
// 756.943 us; speedup vs baseline: 2.9078x; 1.6583x over previous
//
#include <hip/hip_runtime.h>
#include <hip/hip_bf16.h>

#define N_NODES 50000
#define N_EDGES 300000
#define IN_DIM 64
#define EMB 256
#define BN_EPS 1e-5f
#define IDX_CAP 1536

typedef _Float16 half8 __attribute__((ext_vector_type(8)));
typedef _Float16 half4 __attribute__((ext_vector_type(4)));
typedef float f32x4 __attribute__((ext_vector_type(4)));

__device__ __forceinline__ f32x4 mfma16(half8 a, half8 b, f32x4 c) {
    return __builtin_amdgcn_mfma_f32_16x16x32_f16(a, b, c, 0, 0, 0);
}

__device__ __forceinline__ void h2f8(half8 v, f32x4& lo, f32x4& hi) {
#pragma unroll
    for (int j = 0; j < 4; j++) { lo[j] = (float)v[j]; hi[j] = (float)v[4 + j]; }
}

// ---------------- weight packing (once per launch) ----------------
__global__ void pack_weights(const float* __restrict__ W1, const float* __restrict__ W2,
                             const float* __restrict__ Wenc, _Float16* __restrict__ wp) {
    int cid = blockIdx.x * 256 + threadIdx.x;
    if (cid < 18 * 8192) {
        int w = cid >> 13;
        int rem = cid & 8191;
        int nt = rem >> 9;
        int ks = (rem >> 6) & 7;
        int lane = rem & 63;
        int li = w >> 1;
        const float* src = ((w & 1) ? W2 : W1) + (size_t)li * EMB * EMB;
        _Float16* dst = wp + (size_t)cid * 8;
        int n = nt * 16 + (lane & 15);
        int kb = ks * 32 + (lane >> 4) * 8;
#pragma unroll
        for (int j = 0; j < 8; j++) dst[j] = (_Float16)src[(kb + j) * EMB + n];
    } else if (cid < 18 * 8192 + 2048) {
        int c = cid - 18 * 8192;
        int nt = c >> 7;
        int ks = (c >> 6) & 1;
        int lane = c & 63;
        _Float16* dst = wp + (size_t)18 * 65536 + (size_t)c * 8;
        int n = nt * 16 + (lane & 15);
        int kb = ks * 32 + (lane >> 4) * 8;
#pragma unroll
        for (int j = 0; j < 8; j++) dst[j] = (_Float16)Wenc[(kb + j) * EMB + n];
    }
}

// ---------------- CSR build ----------------
__global__ void edge_count(const int* __restrict__ dst, unsigned* __restrict__ counts) {
    int e = blockIdx.x * 256 + threadIdx.x;
    if (e < N_EDGES) atomicAdd(&counts[dst[e]], 1u);
}

__global__ void scan_kernel(const unsigned* __restrict__ counts,
                            unsigned* __restrict__ rowptr, unsigned* __restrict__ cursor) {
    __shared__ unsigned wsum[16];
    __shared__ unsigned run;
    int t = threadIdx.x, wv = t >> 6, lane = t & 63;
    if (t == 0) { run = 0; rowptr[0] = 0; }
    __syncthreads();
    for (int base = 0; base < N_NODES; base += 1024) {
        int i = base + t;
        unsigned v = (i < N_NODES) ? counts[i] : 0u;
        unsigned x = v;
#pragma unroll
        for (int off = 1; off < 64; off <<= 1) {
            unsigned y = __shfl_up(x, off, 64);
            if (lane >= off) x += y;
        }
        if (lane == 63) wsum[wv] = x;
        __syncthreads();
        if (wv == 0) {
            unsigned s = (lane < 16) ? wsum[lane] : 0u;
#pragma unroll
            for (int off = 1; off < 16; off <<= 1) {
                unsigned y = __shfl_up(s, off, 64);
                if (lane >= off) s += y;
            }
            if (lane < 16) wsum[lane] = s;
        }
        __syncthreads();
        unsigned waveoff = (wv > 0) ? wsum[wv - 1] : 0u;
        unsigned incl = run + waveoff + x;
        if (i < N_NODES) { rowptr[i + 1] = incl; cursor[i] = incl - v; }
        __syncthreads();
        if (t == 1023) run = incl;
        __syncthreads();
    }
}

__global__ void edge_fill(const int* __restrict__ src, const int* __restrict__ dst,
                          unsigned* __restrict__ cursor, unsigned* __restrict__ csr_src) {
    int e = blockIdx.x * 256 + threadIdx.x;
    if (e < N_EDGES) {
        unsigned pos = atomicAdd(&cursor[dst[e]], 1u);
        csr_src[pos] = (unsigned)src[e];
    }
}

// ---------------- encoder: g = x @ Wenc + benc (fp16 out) ----------------
__global__ void __launch_bounds__(256) enc_kernel(const float* __restrict__ x,
                                                  const _Float16* __restrict__ wenc,
                                                  const float* __restrict__ benc,
                                                  _Float16* __restrict__ g) {
    int t = threadIdx.x, w = t >> 6, lane = t & 63;
    int rl = lane & 15, khi = lane >> 4;
    int row0 = blockIdx.x * 64;
    f32x4 acc[4][4];
#pragma unroll
    for (int rf = 0; rf < 4; rf++)
#pragma unroll
        for (int nt = 0; nt < 4; nt++) acc[rf][nt] = (f32x4){0.f, 0.f, 0.f, 0.f};
    const half8* bp = (const half8*)wenc + (size_t)(w * 4) * 128 + lane;
#pragma unroll
    for (int ks = 0; ks < 2; ks++) {
        half8 a[4];
#pragma unroll
        for (int rf = 0; rf < 4; rf++) {
            int n = row0 + rf * 16 + rl;
            f32x4 a0 = (f32x4){0.f,0.f,0.f,0.f}, a1 = (f32x4){0.f,0.f,0.f,0.f};
            if (n < N_NODES) {
                const float* ap = x + (size_t)n * IN_DIM + ks * 32 + khi * 8;
                a0 = *(const f32x4*)ap;
                a1 = *(const f32x4*)(ap + 4);
            }
#pragma unroll
            for (int j = 0; j < 4; j++) { a[rf][j] = (_Float16)a0[j]; a[rf][4 + j] = (_Float16)a1[j]; }
        }
        half8 b[4];
#pragma unroll
        for (int nt = 0; nt < 4; nt++) b[nt] = bp[nt * 128 + ks * 64];
#pragma unroll
        for (int rf = 0; rf < 4; rf++)
#pragma unroll
            for (int nt = 0; nt < 4; nt++) acc[rf][nt] = mfma16(a[rf], b[nt], acc[rf][nt]);
    }
#pragma unroll
    for (int nt = 0; nt < 4; nt++) {
        int col = w * 64 + nt * 16 + rl;
        float bias = benc[col];
#pragma unroll
        for (int rf = 0; rf < 4; rf++)
#pragma unroll
            for (int r = 0; r < 4; r++) {
                int n = row0 + rf * 16 + khi * 4 + r;
                if (n < N_NODES) g[(size_t)n * EMB + col] = (_Float16)(acc[rf][nt][r] + bias);
            }
    }
}

// ---------------- fused conv: LDS-staged-CSR gather -> MLP(2 GEMMs) -> [stats] ----------------
__global__ void __launch_bounds__(256, 4) conv_kernel(
    const _Float16* __restrict__ gin, const unsigned* __restrict__ rowptr,
    const unsigned* __restrict__ csr_src,
    const _Float16* __restrict__ w1p, const float* __restrict__ b1,
    const _Float16* __restrict__ w2p, const float* __restrict__ b2,
    _Float16* __restrict__ gout_h, float* __restrict__ gout_f,
    const float* __restrict__ ssp, float* __restrict__ statp, int relu_out)
{
    __shared__ __align__(16) _Float16 zt[64 * 256];   // 32 KB: z tile, then T tile
    __shared__ unsigned lidx[IDX_CAP];                // 6 KB staged edge indices
    __shared__ unsigned lrp[68];                      // staged rowptr[row0 .. row0+64]
    int t = threadIdx.x, w = t >> 6, lane = t & 63;
    int rl = lane & 15, khi = lane >> 4;
    int hw = lane >> 5, hl = lane & 31;               // half-wave id / lane-in-half
    int row0 = blockIdx.x * 64;

    // ---- stage rowptr slice ----
    if (t < 65) {
        int rr = row0 + t;
        lrp[t] = rowptr[rr < N_NODES ? rr : N_NODES];
    }
    __syncthreads();
    unsigned ebase = lrp[0];
    unsigned etot = lrp[64] - ebase;
    unsigned ecnt = etot < IDX_CAP ? etot : IDX_CAP;
    for (unsigned i = t; i < ecnt; i += 256) lidx[i] = csr_src[ebase + i];
    __syncthreads();

    const half8* g8 = (const half8*)gin;
    bool affine = (ssp != nullptr);
    // per-lane columns for gather: hl*8 .. hl*8+7
    f32x4 scLo = (f32x4){1.f,1.f,1.f,1.f}, scHi = scLo;
    f32x4 shLo = (f32x4){0.f,0.f,0.f,0.f}, shHi = shLo;
    if (affine) {
        scLo = *(const f32x4*)&ssp[hl * 8];
        scHi = *(const f32x4*)&ssp[hl * 8 + 4];
        shLo = *(const f32x4*)&ssp[EMB + hl * 8];
        shHi = *(const f32x4*)&ssp[EMB + hl * 8 + 4];
    }
    auto tvL = [&](f32x4 v) -> f32x4 {
        if (affine) {
#pragma unroll
            for (int j = 0; j < 4; j++) v[j] = fmaxf(v[j] * scLo[j] + shLo[j], 0.f);
        }
        return v;
    };
    auto tvH = [&](f32x4 v) -> f32x4 {
        if (affine) {
#pragma unroll
            for (int j = 0; j < 4; j++) v[j] = fmaxf(v[j] * scHi[j] + shHi[j], 0.f);
        }
        return v;
    };

    // ---- gather: each half-wave owns 8 rows; 8-edge branchless batches ----
    int rbase = w * 16 + hw * 8;
    auto do_gather = [&](auto fetch_idx) {
        for (int rr = 0; rr < 8; rr++) {
            int rloc = rbase + rr;
            int n = row0 + rloc;
            f32x4 aLo = (f32x4){0.f,0.f,0.f,0.f}, aHi = (f32x4){0.f,0.f,0.f,0.f};
            if (n < N_NODES) {
                half8 sv = g8[(size_t)n * 32 + hl];
                f32x4 l, h; h2f8(sv, l, h);
                aLo = tvL(l); aHi = tvH(h);
                unsigned beg = lrp[rloc], end = lrp[rloc + 1];
                for (unsigned e = beg; e < end; e += 8) {
                    unsigned last = end - 1;
                    unsigned idx[8];
#pragma unroll
                    for (int j = 0; j < 8; j++) {
                        unsigned ee = e + j; ee = ee < last ? ee : last;
                        idx[j] = fetch_idx(ee);
                    }
                    half8 v[8];
#pragma unroll
                    for (int j = 0; j < 8; j++) v[j] = g8[(size_t)idx[j] * 32 + hl];
#pragma unroll
                    for (int j = 0; j < 8; j++) {
                        float m = (e + j < end) ? 1.f : 0.f;
                        f32x4 vl, vh; h2f8(v[j], vl, vh);
                        aLo += tvL(vl) * m;
                        aHi += tvH(vh) * m;
                    }
                }
            }
            half8 hz;
#pragma unroll
            for (int j = 0; j < 4; j++) { hz[j] = (_Float16)aLo[j]; hz[4 + j] = (_Float16)aHi[j]; }
            *(half8*)&zt[rloc * 256 + ((hl * 8) ^ ((rloc & 15) << 3))] = hz;
        }
    };
    if (etot <= IDX_CAP) do_gather([&](unsigned ee) { return lidx[ee - ebase]; });
    else                 do_gather([&](unsigned ee) { return csr_src[ee]; });
    __syncthreads();

    // ---- stage 1: T = relu(z @ W1 + b1), wave w owns cols [w*64, w*64+64) ----
    f32x4 acc1[4][4];
#pragma unroll
    for (int rf = 0; rf < 4; rf++)
#pragma unroll
        for (int nt = 0; nt < 4; nt++) acc1[rf][nt] = (f32x4){0.f, 0.f, 0.f, 0.f};
    {
        const half8* bp = (const half8*)w1p + (size_t)(w * 4) * 512 + lane;
#pragma unroll
        for (int ks = 0; ks < 8; ks++) {
            half8 a[4];
#pragma unroll
            for (int rf = 0; rf < 4; rf++) {
                int row = rf * 16 + rl;
                a[rf] = *(const half8*)&zt[row * 256 + ((ks * 32 + khi * 8) ^ ((row & 15) << 3))];
            }
            half8 b[4];
#pragma unroll
            for (int nt = 0; nt < 4; nt++) b[nt] = bp[nt * 512 + ks * 64];
#pragma unroll
            for (int rf = 0; rf < 4; rf++)
#pragma unroll
                for (int nt = 0; nt < 4; nt++) acc1[rf][nt] = mfma16(a[rf], b[nt], acc1[rf][nt]);
        }
    }
    __syncthreads();
#pragma unroll
    for (int nt = 0; nt < 4; nt++) {
        int col = w * 64 + nt * 16 + rl;
        float bias = b1[col];
#pragma unroll
        for (int rf = 0; rf < 4; rf++)
#pragma unroll
            for (int r = 0; r < 4; r++) {
                int row = rf * 16 + khi * 4 + r;
                float v = fmaxf(acc1[rf][nt][r] + bias, 0.f);
                zt[row * 256 + (col ^ ((row & 15) << 3))] = (_Float16)v;
            }
    }
    __syncthreads();

    // ---- stage 2: g = T @ W2 + b2 (+relu) ----
    f32x4 acc2[4][4];
#pragma unroll
    for (int rf = 0; rf < 4; rf++)
#pragma unroll
        for (int nt = 0; nt < 4; nt++) acc2[rf][nt] = (f32x4){0.f, 0.f, 0.f, 0.f};
    {
        const half8* bp = (const half8*)w2p + (size_t)(w * 4) * 512 + lane;
#pragma unroll
        for (int ks = 0; ks < 8; ks++) {
            half8 a[4];
#pragma unroll
            for (int rf = 0; rf < 4; rf++) {
                int row = rf * 16 + rl;
                a[rf] = *(const half8*)&zt[row * 256 + ((ks * 32 + khi * 8) ^ ((row & 15) << 3))];
            }
            half8 b[4];
#pragma unroll
            for (int nt = 0; nt < 4; nt++) b[nt] = bp[nt * 512 + ks * 64];
#pragma unroll
            for (int rf = 0; rf < 4; rf++)
#pragma unroll
                for (int nt = 0; nt < 4; nt++) acc2[rf][nt] = mfma16(a[rf], b[nt], acc2[rf][nt]);
        }
    }
    bool wf = (gout_f != nullptr);
#pragma unroll
    for (int nt = 0; nt < 4; nt++) {
        int col = w * 64 + nt * 16 + rl;
        float bias = b2[col];
        float sS = 0.f, s2S = 0.f;
#pragma unroll
        for (int rf = 0; rf < 4; rf++)
#pragma unroll
            for (int r = 0; r < 4; r++) {
                int row = rf * 16 + khi * 4 + r;
                int n = row0 + row;
                float v = acc2[rf][nt][r] + bias;
                if (relu_out) v = fmaxf(v, 0.f);
                if (n < N_NODES) {
                    if (wf) gout_f[(size_t)n * EMB + col] = v;
                    else    gout_h[(size_t)n * EMB + col] = (_Float16)v;
                    sS += v; s2S += v * v;
                }
            }
        if (statp) {
            sS += __shfl_xor(sS, 16); s2S += __shfl_xor(s2S, 16);
            sS += __shfl_xor(sS, 32); s2S += __shfl_xor(s2S, 32);
            if (khi == 0) {
                atomicAdd(&statp[col], sS);
                atomicAdd(&statp[EMB + col], s2S);
            }
        }
    }
}

// ---------------- batchnorm finalize + final apply ----------------
__global__ void bn_finalize(const float* __restrict__ stats, const float* __restrict__ gamma,
                            const float* __restrict__ beta, float* __restrict__ ss) {
    int c = threadIdx.x;
    float mean = stats[c] * (1.f / N_NODES);
    float var = stats[EMB + c] * (1.f / N_NODES) - mean * mean;
    float scale = gamma[c] * rsqrtf(var + BN_EPS);
    ss[c] = scale;
    ss[EMB + c] = beta[c] - mean * scale;
}

__global__ void bn_apply(const float* __restrict__ gin, const float* __restrict__ ss,
                         float* __restrict__ gout) {
    int i = blockIdx.x * 256 + threadIdx.x;
    if (i >= N_NODES * 64) return;
    int c4 = (i & 63) * 4;
    f32x4 v = ((const f32x4*)gin)[i];
    f32x4 sc = *(const f32x4*)&ss[c4];
    f32x4 sh = *(const f32x4*)&ss[EMB + c4];
    f32x4 r;
#pragma unroll
    for (int j = 0; j < 4; j++) r[j] = v[j] * sc[j] + sh[j];
    ((f32x4*)gout)[i] = r;
}

extern "C" void kernel_launch(void* const* d_in, const int* in_sizes, int n_in,
                              void* d_out, int out_size, void* d_ws, size_t ws_size,
                              hipStream_t stream) {
    const float* x     = (const float*)d_in[0];
    const int*   ei    = (const int*)d_in[1];
    const float* Wenc  = (const float*)d_in[2];
    const float* benc  = (const float*)d_in[3];
    const float* W1    = (const float*)d_in[4];
    const float* b1    = (const float*)d_in[5];
    const float* W2    = (const float*)d_in[6];
    const float* b2    = (const float*)d_in[7];
    const float* gamma = (const float*)d_in[8];
    const float* beta  = (const float*)d_in[9];
    float* out = (float*)d_out;

    char* p = (char*)d_ws;
    auto alloc = [&](size_t bytes) { void* q = (void*)p; p += (bytes + 255) & ~(size_t)255; return q; };
    _Float16*  gh0     = (_Float16*)alloc((size_t)N_NODES * EMB * 2);
    _Float16*  gh1     = (_Float16*)alloc((size_t)N_NODES * EMB * 2);
    _Float16*  wp      = (_Float16*)alloc((size_t)(18 * 65536 + 16384) * 2);
    unsigned*  counts  = (unsigned*)alloc((size_t)N_NODES * 4);
    unsigned*  rowptr  = (unsigned*)alloc((size_t)(N_NODES + 1) * 4);
    unsigned*  cursor  = (unsigned*)alloc((size_t)N_NODES * 4);
    unsigned*  csr_src = (unsigned*)alloc((size_t)N_EDGES * 4);
    float*     stats   = (float*)alloc(3 * 512 * 4);
    float*     ss      = (float*)alloc(3 * 512 * 4);

    hipMemsetAsync(counts, 0, (size_t)N_NODES * 4, stream);
    hipMemsetAsync(stats, 0, 3 * 512 * 4, stream);
    pack_weights<<<584, 256, 0, stream>>>(W1, W2, Wenc, wp);
    edge_count<<<(N_EDGES + 255) / 256, 256, 0, stream>>>(ei + N_EDGES, counts);
    scan_kernel<<<1, 1024, 0, stream>>>(counts, rowptr, cursor);
    edge_fill<<<(N_EDGES + 255) / 256, 256, 0, stream>>>(ei, ei + N_EDGES, cursor, csr_src);

    enc_kernel<<<782, 256, 0, stream>>>(x, wp + (size_t)18 * 65536, benc, gh0);

    _Float16* cur = gh0;
    _Float16* nxt = gh1;
    for (int l = 0; l < 3; l++) {
        for (int i = 0; i < 3; i++) {
            int li = l * 3 + i;
            bool last = (l == 2 && i == 2);
            const float* ssp = (i == 0 && l > 0) ? (ss + (size_t)(l - 1) * 512) : nullptr;
            float* statp = (i == 2) ? (stats + (size_t)l * 512) : nullptr;
            conv_kernel<<<782, 256, 0, stream>>>(
                cur, rowptr, csr_src,
                wp + (size_t)(li * 2) * 65536, b1 + li * EMB,
                wp + (size_t)(li * 2 + 1) * 65536, b2 + li * EMB,
                last ? nullptr : nxt, last ? out : nullptr,
                ssp, statp, (i < 2) ? 1 : 0);
            if (!last) { _Float16* tmp = cur; cur = nxt; nxt = tmp; }
        }
        bn_finalize<<<1, 256, 0, stream>>>(stats + (size_t)l * 512, gamma + l * EMB,
                                           beta + l * EMB, ss + (size_t)l * 512);
    }
    bn_apply<<<(N_NODES * 64 + 255) / 256, 256, 0, stream>>>(out, ss + 2 * 512, out);
}